// Round 25
// baseline (163.296 us; speedup 1.0000x reference)
//
#include <hip/hip_runtime.h>
#include <hip/hip_bf16.h>

typedef __bf16 bf16x8 __attribute__((ext_vector_type(8)));
typedef float f32x4 __attribute__((ext_vector_type(4)));

static __device__ __forceinline__ __bf16 tobf(float x) {
    __hip_bfloat16 h = __float2bfloat16(x);
    __bf16 r;
    __builtin_memcpy(&r, &h, 2);
    return r;
}

// fast 2^x: single v_exp_f32 (no libm range-fixup code)
static __device__ __forceinline__ float fexp2(float x) {
    float r;
    asm("v_exp_f32 %0, %1" : "=v"(r) : "v"(x));
    return r;
}

// ---------------------------------------------------------------------------
// Fused prep: (a) x fp32 -> bf16 (vectorized), (b) W_attn^T with qscale
// folded into Q columns, (c) W_proj^T.
// ---------------------------------------------------------------------------
__global__ __launch_bounds__(256) void prep_k(const float* __restrict__ x,
                                              __hip_bfloat16* __restrict__ x_bf,
                                              const float* __restrict__ Wa,
                                              __hip_bfloat16* __restrict__ WaT,
                                              const float* __restrict__ Wp,
                                              __hip_bfloat16* __restrict__ WpT) {
    __shared__ float tile[32][33];
    const int bid = blockIdx.x;
    const int tid = threadIdx.x;
    if (bid < 8192) {
        int i = bid * 256 + tid;
        float4 v = reinterpret_cast<const float4*>(x)[i];
        __hip_bfloat16 a = __float2bfloat16(v.x);
        __hip_bfloat16 b = __float2bfloat16(v.y);
        __hip_bfloat16 c = __float2bfloat16(v.z);
        __hip_bfloat16 d = __float2bfloat16(v.w);
        ushort4 o;
        o.x = *reinterpret_cast<unsigned short*>(&a);
        o.y = *reinterpret_cast<unsigned short*>(&b);
        o.z = *reinterpret_cast<unsigned short*>(&c);
        o.w = *reinterpret_cast<unsigned short*>(&d);
        reinterpret_cast<ushort4*>(x_bf)[i] = o;
        return;
    }
    const float* in;
    __hip_bfloat16* out;
    int bx, Cn, qrows;
    float qscale;
    int t;
    if (bid < 8192 + 3072) {
        t = bid - 8192;
        in = Wa; out = WaT; Cn = 3072; qrows = 1024;
        qscale = 0.045084223f;  // log2(e)/sqrt(1024)
        bx = t % 96;
    } else {
        t = bid - 11264;
        in = Wp; out = WpT; Cn = 1024; qrows = 0;
        qscale = 1.0f;
        bx = t % 32;
    }
    const int by = (bid < 11264) ? (t / 96) : (t / 32);
    const int R = 1024;
    const int c0 = bx * 32, r0 = by * 32;
    const int tx = tid & 31, ty = tid >> 5;  // 32 x 8
#pragma unroll
    for (int i = 0; i < 4; ++i)
        tile[ty + i * 8][tx] = in[(size_t)(r0 + ty + i * 8) * Cn + c0 + tx];
    __syncthreads();
#pragma unroll
    for (int i = 0; i < 4; ++i) {
        int orow = c0 + ty + i * 8;
        float v = tile[tx][ty + i * 8];
        if (orow < qrows) v *= qscale;
        out[(size_t)orow * R + r0 + tx] = __float2bfloat16(v);
    }
}

// ---------------------------------------------------------------------------
// bf16 GEMM, 4 waves, BM=128 x BN=128, BK=64, double-buffered LDS, ONE
// barrier + vmcnt(0) per K-tile. FUSE_VT: V-column blocks transposed +
// key-permuted through LDS with coalesced 16B stores (round-24, measured).
// ---------------------------------------------------------------------------
template <bool OUT_BF16, bool FUSE_VT>
__global__ __launch_bounds__(256, 2) void gemm4w(const __hip_bfloat16* __restrict__ A,
                                                 const __hip_bfloat16* __restrict__ Bt,
                                                 __hip_bfloat16* __restrict__ Cb,
                                                 float* __restrict__ Cf,
                                                 __hip_bfloat16* __restrict__ VtOut,
                                                 int M, int N, int K) {
    __shared__ __attribute__((aligned(16))) char As[2][128 * 128];  // 128 rows x 64 k
    __shared__ __attribute__((aligned(16))) char Bs[2][128 * 128];
    const int tid = threadIdx.x;
    const int lane = tid & 63, wid = tid >> 6;
    const int l15 = lane & 15, lg = lane >> 4;
    const int wr = wid >> 1, wc = wid & 1;
    const int lin = blockIdx.y * gridDim.x + blockIdx.x;
    const int cpx = (gridDim.x * gridDim.y) >> 3;
    const int sw = (lin & 7) * cpx + (lin >> 3);
    const int bn = sw % gridDim.x, bm = sw / gridDim.x;
    const size_t arow0 = (size_t)bm * 128;
    const size_t brow0 = (size_t)bn * 128;

    f32x4 acc[4][4] = {};

    const __hip_bfloat16* pa[4];
    const __hip_bfloat16* pb[4];
#pragma unroll
    for (int p = 0; p < 4; ++p) {
        int idx = p * 256 + tid;
        int row = idx >> 3, c = idx & 7;
        int col = 8 * (c ^ (row & 7));
        pa[p] = A + (arow0 + row) * (size_t)K + col;
        pb[p] = Bt + (brow0 + row) * (size_t)K + col;
    }

    auto stage = [&](int buf) {
        char* Ad = buf ? &As[1][0] : &As[0][0];
        char* Bd = buf ? &Bs[1][0] : &Bs[0][0];
#pragma unroll
        for (int p = 0; p < 4; ++p) {
            __builtin_amdgcn_global_load_lds(
                (const __attribute__((address_space(1))) void*)pa[p],
                (__attribute__((address_space(3))) void*)(Ad + (p * 256 + tid) * 16), 16, 0, 0);
            __builtin_amdgcn_global_load_lds(
                (const __attribute__((address_space(1))) void*)pb[p],
                (__attribute__((address_space(3))) void*)(Bd + (p * 256 + tid) * 16), 16, 0, 0);
            pa[p] += 64;
            pb[p] += 64;
        }
    };

    stage(0);
    asm volatile("s_waitcnt vmcnt(0)" ::: "memory");
    __syncthreads();

    const int nk = K >> 6;
    int cur = 0;
    for (int kt = 0; kt < nk; ++kt) {
        if (kt + 1 < nk) stage(cur ^ 1);
        const char* Ab = cur ? &As[1][0] : &As[0][0];
        const char* Bb = cur ? &Bs[1][0] : &Bs[0][0];
#pragma unroll
        for (int ks = 0; ks < 2; ++ks) {
            bf16x8 af[4], bfr[4];
#pragma unroll
            for (int mf = 0; mf < 4; ++mf) {
                int R = wr * 64 + mf * 16 + l15;
                af[mf] = *reinterpret_cast<const bf16x8*>(
                    Ab + R * 128 + 16 * ((ks * 4 + lg) ^ (R & 7)));
            }
#pragma unroll
            for (int nf = 0; nf < 4; ++nf) {
                int R = wc * 64 + nf * 16 + l15;
                bfr[nf] = *reinterpret_cast<const bf16x8*>(
                    Bb + R * 128 + 16 * ((ks * 4 + lg) ^ (R & 7)));
            }
            __builtin_amdgcn_s_setprio(1);
#pragma unroll
            for (int mf = 0; mf < 4; ++mf)
#pragma unroll
                for (int nf = 0; nf < 4; ++nf)
                    acc[mf][nf] = __builtin_amdgcn_mfma_f32_16x16x32_bf16(af[mf], bfr[nf],
                                                                          acc[mf][nf], 0, 0, 0);
            __builtin_amdgcn_s_setprio(0);
        }
        asm volatile("s_waitcnt vmcnt(0)" ::: "memory");
        __syncthreads();
        cur ^= 1;
    }

    if (FUSE_VT && bn >= 16) {
        const int trow0 = bm * 128;
        const int b = trow0 >> 11;
        const int t0 = trow0 & 2047;
        const int cv0 = bn * 128 - 2048;
        __hip_bfloat16* lds = reinterpret_cast<__hip_bfloat16*>(&As[0][0]);  // 64 x 136
#pragma unroll 1
        for (int pass = 0; pass < 2; ++pass) {
            __syncthreads();
            if (wr == pass) {
#pragma unroll
                for (int mf = 0; mf < 4; ++mf)
#pragma unroll
                    for (int nf = 0; nf < 4; ++nf)
#pragma unroll
                        for (int j = 0; j < 4; ++j) {
                            int rloc = mf * 16 + lg * 4 + j;
                            int col = wc * 64 + nf * 16 + l15;
                            lds[rloc * 136 + col] = __float2bfloat16(acc[mf][nf][j]);
                        }
            }
            __syncthreads();
#pragma unroll
            for (int q = 0; q < 4; ++q) {
                int u = q * 256 + tid;
                int vr = u >> 3, oc = u & 7;
                bf16x8 o;
#pragma unroll
                for (int e = 0; e < 8; ++e) {
                    int s = oc * 8 + e;
                    int slot = s & 31;
                    int r = (slot & 3) | (((slot >> 3) & 3) << 2) | (((slot >> 2) & 1) << 4);
                    int tsrc = (s & 32) | r;
                    o[e] = tobf(__bfloat162float(lds[tsrc * 136 + vr]));
                }
                size_t vrow = (size_t)b * 1024 + cv0 + vr;
                *reinterpret_cast<bf16x8*>(&VtOut[vrow * 2048 + t0 + pass * 64 + oc * 8]) = o;
            }
        }
        return;
    }

#pragma unroll
    for (int mf = 0; mf < 4; ++mf) {
#pragma unroll
        for (int nf = 0; nf < 4; ++nf) {
#pragma unroll
            for (int j = 0; j < 4; ++j) {
                int row = bm * 128 + wr * 64 + mf * 16 + lg * 4 + j;
                int col = bn * 128 + wc * 64 + nf * 16 + l15;
                if (OUT_BF16)
                    Cb[(size_t)row * N + col] = __float2bfloat16(acc[mf][nf][j]);
                else
                    Cf[(size_t)row * N + col] = acc[mf][nf][j];
            }
        }
    }
}

// ---------------------------------------------------------------------------
// Flash attention (causal), swapped-QK^T, key-permuted V, MAX-FREE softmax,
// MFMA ROW-SUM. NEW: 64 Q-ROWS PER WAVE (4 m-frags), 2-wave blocks — the
// K/V LDS fragment reads per wave per tile are unchanged (16 x b128) but
// now amortize over 2x the q rows, HALVING per-CU LDS-read traffic per unit
// work (the quantified bottleneck: ~77% LDS-pipe busy at 32 rows/wave).
// m-frags processed serially (pa transient) to keep VGPR < 256.
// Grid (bh=64, y=16), one super-tile per block, heavy first.
// ---------------------------------------------------------------------------
__global__ __launch_bounds__(128, 2) void attn_k(const __hip_bfloat16* __restrict__ qkv,
                                                 const __hip_bfloat16* __restrict__ Vt,
                                                 __hip_bfloat16* __restrict__ y) {
    constexpr int TT = 2048;
    constexpr int S3C = 3072;
    const int bh = blockIdx.x, b = bh >> 4, h = bh & 15;
    const int st = 15 - (int)blockIdx.y;  // heavy first
    const int tid = threadIdx.x;
    const int wid = tid >> 6, lane = tid & 63;
    const int l15 = lane & 15, lg = lane >> 4;

    __shared__ __attribute__((aligned(16))) char Ks[2][64 * 128];  // [key][d-chunk^swz]
    __shared__ __attribute__((aligned(16))) char Vs[2][64 * 128];  // [d][key-chunk^swz]

    const __hip_bfloat16* base = qkv + (size_t)b * TT * S3C;
    const int qo = h * 64, ko = 1024 + h * 64;
    const __hip_bfloat16* vt = Vt + (size_t)bh * 64 * TT;

    bf16x8 vones;
#pragma unroll
    for (int i = 0; i < 8; ++i) vones[i] = tobf(1.0f);

    const int qbase = st * 128 + wid * 64;
    const int my_nt = (qbase >> 6) + 1;  // tiles this wave computes
    const int blk_nt = st * 2 + 2;       // tiles the block stages

    // Q B-fragments: 4 m-frags x 2 d-halves
    bf16x8 aq[4][2];
#pragma unroll
    for (int m = 0; m < 4; ++m) {
        const __hip_bfloat16* qp = base + (size_t)(qbase + m * 16 + l15) * S3C + qo + lg * 8;
        aq[m][0] = *reinterpret_cast<const bf16x8*>(qp);
        aq[m][1] = *reinterpret_cast<const bf16x8*>(qp + 32);
    }

    f32x4 acc[4][4] = {};  // [m][dg]: row=q(lg*4+j), col=d(dg*16+l15)
    f32x4 lsum[4] = {};    // MFMA row-sums

    // staging: 4 x 16B units per thread for K and V each (128 threads)
    const __hip_bfloat16* kp[4];
    const __hip_bfloat16* vp[4];
#pragma unroll
    for (int p = 0; p < 4; ++p) {
        int idx = p * 128 + tid;
        int row = idx >> 3, c = idx & 7;
        int col = 8 * (c ^ (row & 7));
        kp[p] = base + (size_t)row * S3C + ko + col;
        vp[p] = vt + (size_t)row * TT + col;
    }

    auto stage = [&](int buf) {
        char* Kd = buf ? &Ks[1][0] : &Ks[0][0];
        char* Vd = buf ? &Vs[1][0] : &Vs[0][0];
#pragma unroll
        for (int p = 0; p < 4; ++p) {
            __builtin_amdgcn_global_load_lds(
                (const __attribute__((address_space(1))) void*)kp[p],
                (__attribute__((address_space(3))) void*)(Kd + (p * 128 + tid) * 16), 16, 0, 0);
            __builtin_amdgcn_global_load_lds(
                (const __attribute__((address_space(1))) void*)vp[p],
                (__attribute__((address_space(3))) void*)(Vd + (p * 128 + tid) * 16), 16, 0, 0);
            kp[p] += (size_t)64 * S3C;
            vp[p] += 64;
        }
    };

    stage(0);
    asm volatile("s_waitcnt vmcnt(0)" ::: "memory");
    __syncthreads();

    int cur = 0;
    for (int kt = 0; kt < blk_nt; ++kt) {
        if (kt + 1 < blk_nt) stage(cur ^ 1);
        if (kt < my_nt) {
            const int kb = kt * 64;
            const char* Kb = cur ? &Ks[1][0] : &Ks[0][0];
            const char* Vb = cur ? &Vs[1][0] : &Vs[0][0];
            const int swl = l15 & 7;
            // ---- K fragments (8 b128 reads; shared by all 4 m-frags)
            bf16x8 kf[4][2];
#pragma unroll
            for (int cg = 0; cg < 4; ++cg) {
                const char* krow = Kb + (cg * 16 + l15) * 128;
                kf[cg][0] = *reinterpret_cast<const bf16x8*>(krow + 16 * (lg ^ swl));
                kf[cg][1] = *reinterpret_cast<const bf16x8*>(krow + 16 * ((4 + lg) ^ swl));
            }
            // ---- V fragments (8 b128 reads; shared by all 4 m-frags)
            bf16x8 vb[2][4];
#pragma unroll
            for (int dg = 0; dg < 4; ++dg) {
                const char* vrow = Vb + (dg * 16 + l15) * 128;
                vb[0][dg] = *reinterpret_cast<const bf16x8*>(vrow + 16 * (lg ^ swl));
                vb[1][dg] = *reinterpret_cast<const bf16x8*>(vrow + 16 * ((4 + lg) ^ swl));
            }
            const bool needmask = (kb + 63 > qbase);
            // ---- per m-frag: QK^T -> exp -> pack -> PV (pa transient)
#pragma unroll
            for (int m = 0; m < 4; ++m) {
                f32x4 s[4];
                __builtin_amdgcn_s_setprio(1);
#pragma unroll
                for (int cg = 0; cg < 4; ++cg) {
                    f32x4 z = {0.f, 0.f, 0.f, 0.f};
                    z = __builtin_amdgcn_mfma_f32_16x16x32_bf16(kf[cg][0], aq[m][0], z, 0, 0, 0);
                    z = __builtin_amdgcn_mfma_f32_16x16x32_bf16(kf[cg][1], aq[m][1], z, 0, 0, 0);
                    s[cg] = z;
                }
                __builtin_amdgcn_s_setprio(0);
                float p[4][4];
#pragma unroll
                for (int cg = 0; cg < 4; ++cg)
#pragma unroll
                    for (int j = 0; j < 4; ++j) {
                        float e = fexp2(s[cg][j]);
                        if (needmask) {
                            int key = kb + cg * 16 + lg * 4 + j;
                            int qrow = qbase + m * 16 + l15;
                            e = (key > qrow) ? 0.f : e;
                        }
                        p[cg][j] = e;
                    }
                bf16x8 pa[2];
#pragma unroll
                for (int ks = 0; ks < 2; ++ks) {
                    bf16x8 t2;
                    t2[0] = tobf(p[2 * ks][0]);
                    t2[1] = tobf(p[2 * ks][1]);
                    t2[2] = tobf(p[2 * ks][2]);
                    t2[3] = tobf(p[2 * ks][3]);
                    t2[4] = tobf(p[2 * ks + 1][0]);
                    t2[5] = tobf(p[2 * ks + 1][1]);
                    t2[6] = tobf(p[2 * ks + 1][2]);
                    t2[7] = tobf(p[2 * ks + 1][3]);
                    pa[ks] = t2;
                }
                __builtin_amdgcn_s_setprio(1);
#pragma unroll
                for (int ks = 0; ks < 2; ++ks) {
#pragma unroll
                    for (int dg = 0; dg < 4; ++dg)
                        acc[m][dg] = __builtin_amdgcn_mfma_f32_16x16x32_bf16(
                            pa[ks], vb[ks][dg], acc[m][dg], 0, 0, 0);
                    lsum[m] = __builtin_amdgcn_mfma_f32_16x16x32_bf16(pa[ks], vones,
                                                                      lsum[m], 0, 0, 0);
                }
                __builtin_amdgcn_s_setprio(0);
            }
        }
        asm volatile("s_waitcnt vmcnt(0)" ::: "memory");
        __syncthreads();
        cur ^= 1;
    }

    // ---- epilogue: lsum already in acc row layout -> no cross-lane ops
#pragma unroll
    for (int m = 0; m < 4; ++m)
#pragma unroll
        for (int j = 0; j < 4; ++j) {
            float inv = 1.f / lsum[m][j];
            int t = qbase + m * 16 + lg * 4 + j;
#pragma unroll
            for (int dg = 0; dg < 4; ++dg) {
                float o = acc[m][dg][j] * inv;
                y[((size_t)(b * TT + t)) * 1024 + h * 64 + dg * 16 + l15] = __float2bfloat16(o);
            }
        }
}

// ---------------------------------------------------------------------------
extern "C" void kernel_launch(void* const* d_in, const int* in_sizes, int n_in,
                              void* d_out, int out_size, void* d_ws, size_t ws_size,
                              hipStream_t stream) {
    const float* x = (const float*)d_in[0];   // [4,2048,1024]
    const float* Wa = (const float*)d_in[1];  // [1024,3072]
    const float* Wp = (const float*)d_in[2];  // [1024,1024]
    float* out = (float*)d_out;               // [4,2048,1024] fp32

    __hip_bfloat16* ws = (__hip_bfloat16*)d_ws;
    __hip_bfloat16* x_bf = ws;                          // 8192*1024
    __hip_bfloat16* WaT = x_bf + (size_t)8192 * 1024;   // 3072*1024 (W_attn^T)
    __hip_bfloat16* WpT = WaT + (size_t)3072 * 1024;    // 1024*1024 (W_proj^T)
    __hip_bfloat16* qkv = WpT + (size_t)1024 * 1024;    // 8192*3072 (V third unused)
    __hip_bfloat16* ybf = qkv + (size_t)8192 * 3072;    // 8192*1024
    __hip_bfloat16* Vt = ybf + (size_t)8192 * 1024;     // 64*64*2048 = 8192*1024

    // fused prep: x cvt + W_attn^T (Q cols scaled by log2e/sqrt(C)) + W_proj^T
    prep_k<<<8192 + 3072 + 1024, 256, 0, stream>>>(x, x_bf, Wa, WaT, Wp, WpT);
    // qkv = x @ W_attn; V columns transposed+key-permuted into Vt via LDS
    gemm4w<true, true><<<dim3(24, 64), 256, 0, stream>>>(x_bf, WaT, qkv, nullptr, Vt,
                                                         8192, 3072, 1024);
    // flash attention -> ybf (2-wave blocks, 64 q-rows/wave, heavy first)
    attn_k<<<dim3(64, 16), 128, 0, stream>>>(qkv, Vt, ybf);
    // out = y @ W_proj   (M=8192, N=1024, K=1024), fp32 out
    gemm4w<false, false><<<dim3(8, 64), 256, 0, stream>>>(ybf, WpT, nullptr, out, nullptr,
                                                          8192, 1024, 1024);
}

// Round 26
// 160.011 us; speedup vs baseline: 1.0205x; 1.0205x over previous
//
#include <hip/hip_runtime.h>
#include <hip/hip_bf16.h>

typedef __bf16 bf16x8 __attribute__((ext_vector_type(8)));
typedef float f32x4 __attribute__((ext_vector_type(4)));

static __device__ __forceinline__ __bf16 tobf(float x) {
    __hip_bfloat16 h = __float2bfloat16(x);
    __bf16 r;
    __builtin_memcpy(&r, &h, 2);
    return r;
}

// fast 2^x: single v_exp_f32 (no libm range-fixup code)
static __device__ __forceinline__ float fexp2(float x) {
    float r;
    asm("v_exp_f32 %0, %1" : "=v"(r) : "v"(x));
    return r;
}

// ---------------------------------------------------------------------------
// Fused prep: (a) x fp32 -> bf16 (vectorized), (b) W_attn^T with qscale
// folded into Q columns, (c) W_proj^T.
// ---------------------------------------------------------------------------
__global__ __launch_bounds__(256) void prep_k(const float* __restrict__ x,
                                              __hip_bfloat16* __restrict__ x_bf,
                                              const float* __restrict__ Wa,
                                              __hip_bfloat16* __restrict__ WaT,
                                              const float* __restrict__ Wp,
                                              __hip_bfloat16* __restrict__ WpT) {
    __shared__ float tile[32][33];
    const int bid = blockIdx.x;
    const int tid = threadIdx.x;
    if (bid < 8192) {
        int i = bid * 256 + tid;
        float4 v = reinterpret_cast<const float4*>(x)[i];
        __hip_bfloat16 a = __float2bfloat16(v.x);
        __hip_bfloat16 b = __float2bfloat16(v.y);
        __hip_bfloat16 c = __float2bfloat16(v.z);
        __hip_bfloat16 d = __float2bfloat16(v.w);
        ushort4 o;
        o.x = *reinterpret_cast<unsigned short*>(&a);
        o.y = *reinterpret_cast<unsigned short*>(&b);
        o.z = *reinterpret_cast<unsigned short*>(&c);
        o.w = *reinterpret_cast<unsigned short*>(&d);
        reinterpret_cast<ushort4*>(x_bf)[i] = o;
        return;
    }
    const float* in;
    __hip_bfloat16* out;
    int bx, Cn, qrows;
    float qscale;
    int t;
    if (bid < 8192 + 3072) {
        t = bid - 8192;
        in = Wa; out = WaT; Cn = 3072; qrows = 1024;
        qscale = 0.045084223f;  // log2(e)/sqrt(1024)
        bx = t % 96;
    } else {
        t = bid - 11264;
        in = Wp; out = WpT; Cn = 1024; qrows = 0;
        qscale = 1.0f;
        bx = t % 32;
    }
    const int by = (bid < 11264) ? (t / 96) : (t / 32);
    const int R = 1024;
    const int c0 = bx * 32, r0 = by * 32;
    const int tx = tid & 31, ty = tid >> 5;  // 32 x 8
#pragma unroll
    for (int i = 0; i < 4; ++i)
        tile[ty + i * 8][tx] = in[(size_t)(r0 + ty + i * 8) * Cn + c0 + tx];
    __syncthreads();
#pragma unroll
    for (int i = 0; i < 4; ++i) {
        int orow = c0 + ty + i * 8;
        float v = tile[tx][ty + i * 8];
        if (orow < qrows) v *= qscale;
        out[(size_t)orow * R + r0 + tx] = __float2bfloat16(v);
    }
}

// ---------------------------------------------------------------------------
// bf16 GEMM, 4 waves, BM=128 x BN=128, BK=64, double-buffered LDS, ONE
// barrier + vmcnt(0) per K-tile. FUSE_VT: V-column blocks transposed +
// key-permuted through LDS with coalesced 16B stores (round-24, measured).
// ---------------------------------------------------------------------------
template <bool OUT_BF16, bool FUSE_VT>
__global__ __launch_bounds__(256, 2) void gemm4w(const __hip_bfloat16* __restrict__ A,
                                                 const __hip_bfloat16* __restrict__ Bt,
                                                 __hip_bfloat16* __restrict__ Cb,
                                                 float* __restrict__ Cf,
                                                 __hip_bfloat16* __restrict__ VtOut,
                                                 int M, int N, int K) {
    __shared__ __attribute__((aligned(16))) char As[2][128 * 128];  // 128 rows x 64 k
    __shared__ __attribute__((aligned(16))) char Bs[2][128 * 128];
    const int tid = threadIdx.x;
    const int lane = tid & 63, wid = tid >> 6;
    const int l15 = lane & 15, lg = lane >> 4;
    const int wr = wid >> 1, wc = wid & 1;
    const int lin = blockIdx.y * gridDim.x + blockIdx.x;
    const int cpx = (gridDim.x * gridDim.y) >> 3;
    const int sw = (lin & 7) * cpx + (lin >> 3);
    const int bn = sw % gridDim.x, bm = sw / gridDim.x;
    const size_t arow0 = (size_t)bm * 128;
    const size_t brow0 = (size_t)bn * 128;

    f32x4 acc[4][4] = {};

    const __hip_bfloat16* pa[4];
    const __hip_bfloat16* pb[4];
#pragma unroll
    for (int p = 0; p < 4; ++p) {
        int idx = p * 256 + tid;
        int row = idx >> 3, c = idx & 7;
        int col = 8 * (c ^ (row & 7));
        pa[p] = A + (arow0 + row) * (size_t)K + col;
        pb[p] = Bt + (brow0 + row) * (size_t)K + col;
    }

    auto stage = [&](int buf) {
        char* Ad = buf ? &As[1][0] : &As[0][0];
        char* Bd = buf ? &Bs[1][0] : &Bs[0][0];
#pragma unroll
        for (int p = 0; p < 4; ++p) {
            __builtin_amdgcn_global_load_lds(
                (const __attribute__((address_space(1))) void*)pa[p],
                (__attribute__((address_space(3))) void*)(Ad + (p * 256 + tid) * 16), 16, 0, 0);
            __builtin_amdgcn_global_load_lds(
                (const __attribute__((address_space(1))) void*)pb[p],
                (__attribute__((address_space(3))) void*)(Bd + (p * 256 + tid) * 16), 16, 0, 0);
            pa[p] += 64;
            pb[p] += 64;
        }
    };

    stage(0);
    asm volatile("s_waitcnt vmcnt(0)" ::: "memory");
    __syncthreads();

    const int nk = K >> 6;
    int cur = 0;
    for (int kt = 0; kt < nk; ++kt) {
        if (kt + 1 < nk) stage(cur ^ 1);
        const char* Ab = cur ? &As[1][0] : &As[0][0];
        const char* Bb = cur ? &Bs[1][0] : &Bs[0][0];
#pragma unroll
        for (int ks = 0; ks < 2; ++ks) {
            bf16x8 af[4], bfr[4];
#pragma unroll
            for (int mf = 0; mf < 4; ++mf) {
                int R = wr * 64 + mf * 16 + l15;
                af[mf] = *reinterpret_cast<const bf16x8*>(
                    Ab + R * 128 + 16 * ((ks * 4 + lg) ^ (R & 7)));
            }
#pragma unroll
            for (int nf = 0; nf < 4; ++nf) {
                int R = wc * 64 + nf * 16 + l15;
                bfr[nf] = *reinterpret_cast<const bf16x8*>(
                    Bb + R * 128 + 16 * ((ks * 4 + lg) ^ (R & 7)));
            }
            __builtin_amdgcn_s_setprio(1);
#pragma unroll
            for (int mf = 0; mf < 4; ++mf)
#pragma unroll
                for (int nf = 0; nf < 4; ++nf)
                    acc[mf][nf] = __builtin_amdgcn_mfma_f32_16x16x32_bf16(af[mf], bfr[nf],
                                                                          acc[mf][nf], 0, 0, 0);
            __builtin_amdgcn_s_setprio(0);
        }
        asm volatile("s_waitcnt vmcnt(0)" ::: "memory");
        __syncthreads();
        cur ^= 1;
    }

    if (FUSE_VT && bn >= 16) {
        const int trow0 = bm * 128;
        const int b = trow0 >> 11;
        const int t0 = trow0 & 2047;
        const int cv0 = bn * 128 - 2048;
        __hip_bfloat16* lds = reinterpret_cast<__hip_bfloat16*>(&As[0][0]);  // 64 x 136
#pragma unroll 1
        for (int pass = 0; pass < 2; ++pass) {
            __syncthreads();
            if (wr == pass) {
#pragma unroll
                for (int mf = 0; mf < 4; ++mf)
#pragma unroll
                    for (int nf = 0; nf < 4; ++nf)
#pragma unroll
                        for (int j = 0; j < 4; ++j) {
                            int rloc = mf * 16 + lg * 4 + j;
                            int col = wc * 64 + nf * 16 + l15;
                            lds[rloc * 136 + col] = __float2bfloat16(acc[mf][nf][j]);
                        }
            }
            __syncthreads();
#pragma unroll
            for (int q = 0; q < 4; ++q) {
                int u = q * 256 + tid;
                int vr = u >> 3, oc = u & 7;
                bf16x8 o;
#pragma unroll
                for (int e = 0; e < 8; ++e) {
                    int s = oc * 8 + e;
                    int slot = s & 31;
                    int r = (slot & 3) | (((slot >> 3) & 3) << 2) | (((slot >> 2) & 1) << 4);
                    int tsrc = (s & 32) | r;
                    o[e] = tobf(__bfloat162float(lds[tsrc * 136 + vr]));
                }
                size_t vrow = (size_t)b * 1024 + cv0 + vr;
                *reinterpret_cast<bf16x8*>(&VtOut[vrow * 2048 + t0 + pass * 64 + oc * 8]) = o;
            }
        }
        return;
    }

#pragma unroll
    for (int mf = 0; mf < 4; ++mf) {
#pragma unroll
        for (int nf = 0; nf < 4; ++nf) {
#pragma unroll
            for (int j = 0; j < 4; ++j) {
                int row = bm * 128 + wr * 64 + mf * 16 + lg * 4 + j;
                int col = bn * 128 + wc * 64 + nf * 16 + l15;
                if (OUT_BF16)
                    Cb[(size_t)row * N + col] = __float2bfloat16(acc[mf][nf][j]);
                else
                    Cf[(size_t)row * N + col] = acc[mf][nf][j];
            }
        }
    }
}

// ---------------------------------------------------------------------------
// Flash attention (causal), swapped-QK^T, key-permuted V, MAX-FREE softmax,
// MFMA ROW-SUM, 4-WAVE BLOCKS, one super-tile per block, heavy first
// (round-21/24 version — established local optimum ~69.7 us; bracketed by
// more-waves (null) and fewer-fatter-waves (regression) experiments).
// ---------------------------------------------------------------------------
__global__ __launch_bounds__(256) void attn_k(const __hip_bfloat16* __restrict__ qkv,
                                              const __hip_bfloat16* __restrict__ Vt,
                                              __hip_bfloat16* __restrict__ y) {
    constexpr int TT = 2048;
    constexpr int S3C = 3072;
    const int bh = blockIdx.x, b = bh >> 4, h = bh & 15;
    const int st = 15 - (int)blockIdx.y;  // heavy first
    const int tid = threadIdx.x;
    const int wid = tid >> 6, lane = tid & 63;
    const int l15 = lane & 15, lg = lane >> 4;

    __shared__ __attribute__((aligned(16))) char Ks[2][64 * 128];  // [key][d-chunk^swz]
    __shared__ __attribute__((aligned(16))) char Vs[2][64 * 128];  // [d][key-chunk^swz]

    const __hip_bfloat16* base = qkv + (size_t)b * TT * S3C;
    const int qo = h * 64, ko = 1024 + h * 64;
    const __hip_bfloat16* vt = Vt + (size_t)bh * 64 * TT;

    bf16x8 vones;
#pragma unroll
    for (int i = 0; i < 8; ++i) vones[i] = tobf(1.0f);

    const int idx0 = tid, idx1 = 256 + tid;
    const int r0 = idx0 >> 3, c0 = 8 * ((idx0 & 7) ^ (r0 & 7));
    const int r1 = idx1 >> 3, c1 = 8 * ((idx1 & 7) ^ (r1 & 7));

    const int qbase = st * 128 + wid * 32;
    const int my_nt = (qbase >> 6) + 1;  // tiles this wave computes
    const int blk_nt = st * 2 + 2;       // tiles the block stages

    bf16x8 aq[2][2];
#pragma unroll
    for (int m = 0; m < 2; ++m) {
        const __hip_bfloat16* qp = base + (size_t)(qbase + m * 16 + l15) * S3C + qo + lg * 8;
        aq[m][0] = *reinterpret_cast<const bf16x8*>(qp);
        aq[m][1] = *reinterpret_cast<const bf16x8*>(qp + 32);
    }

    f32x4 acc[2][4] = {};  // [m][dg]: row=q(lg*4+j), col=d(dg*16+l15)
    f32x4 lsum[2] = {};

    const __hip_bfloat16* kp0 = base + (size_t)r0 * S3C + ko + c0;
    const __hip_bfloat16* kp1 = base + (size_t)r1 * S3C + ko + c1;
    const __hip_bfloat16* vp0 = vt + (size_t)r0 * TT + c0;
    const __hip_bfloat16* vp1 = vt + (size_t)r1 * TT + c1;

    auto stage = [&](int buf) {
        char* Kd = buf ? &Ks[1][0] : &Ks[0][0];
        char* Vd = buf ? &Vs[1][0] : &Vs[0][0];
        __builtin_amdgcn_global_load_lds(
            (const __attribute__((address_space(1))) void*)kp0,
            (__attribute__((address_space(3))) void*)(Kd + idx0 * 16), 16, 0, 0);
        __builtin_amdgcn_global_load_lds(
            (const __attribute__((address_space(1))) void*)kp1,
            (__attribute__((address_space(3))) void*)(Kd + idx1 * 16), 16, 0, 0);
        __builtin_amdgcn_global_load_lds(
            (const __attribute__((address_space(1))) void*)vp0,
            (__attribute__((address_space(3))) void*)(Vd + idx0 * 16), 16, 0, 0);
        __builtin_amdgcn_global_load_lds(
            (const __attribute__((address_space(1))) void*)vp1,
            (__attribute__((address_space(3))) void*)(Vd + idx1 * 16), 16, 0, 0);
        kp0 += (size_t)64 * S3C;
        kp1 += (size_t)64 * S3C;
        vp0 += 64;
        vp1 += 64;
    };

    stage(0);
    asm volatile("s_waitcnt vmcnt(0)" ::: "memory");
    __syncthreads();

    int cur = 0;
    for (int kt = 0; kt < blk_nt; ++kt) {
        if (kt + 1 < blk_nt) stage(cur ^ 1);
        if (kt < my_nt) {
            const int kb = kt * 64;
            const char* Kb = cur ? &Ks[1][0] : &Ks[0][0];
            const char* Vb = cur ? &Vs[1][0] : &Vs[0][0];
            const int swl = l15 & 7;
            f32x4 s[2][4];
            __builtin_amdgcn_s_setprio(1);
#pragma unroll
            for (int cg = 0; cg < 4; ++cg) {
                const char* krow = Kb + (cg * 16 + l15) * 128;
                bf16x8 k0 = *reinterpret_cast<const bf16x8*>(krow + 16 * (lg ^ swl));
                bf16x8 k1 = *reinterpret_cast<const bf16x8*>(krow + 16 * ((4 + lg) ^ swl));
#pragma unroll
                for (int m = 0; m < 2; ++m) {
                    f32x4 z = {0.f, 0.f, 0.f, 0.f};
                    z = __builtin_amdgcn_mfma_f32_16x16x32_bf16(k0, aq[m][0], z, 0, 0, 0);
                    z = __builtin_amdgcn_mfma_f32_16x16x32_bf16(k1, aq[m][1], z, 0, 0, 0);
                    s[m][cg] = z;
                }
            }
            __builtin_amdgcn_s_setprio(0);
            bf16x8 vb[2][4];
#pragma unroll
            for (int dg = 0; dg < 4; ++dg) {
                const char* vrow = Vb + (dg * 16 + l15) * 128;
                vb[0][dg] = *reinterpret_cast<const bf16x8*>(vrow + 16 * (lg ^ swl));
                vb[1][dg] = *reinterpret_cast<const bf16x8*>(vrow + 16 * ((4 + lg) ^ swl));
            }
            float p[2][4][4];
            const bool needmask = (kb + 63 > qbase);
#pragma unroll
            for (int m = 0; m < 2; ++m)
#pragma unroll
                for (int cg = 0; cg < 4; ++cg)
#pragma unroll
                    for (int j = 0; j < 4; ++j) {
                        float e = fexp2(s[m][cg][j]);
                        if (needmask) {
                            int key = kb + cg * 16 + lg * 4 + j;
                            int qrow = qbase + m * 16 + l15;
                            e = (key > qrow) ? 0.f : e;
                        }
                        p[m][cg][j] = e;
                    }
            bf16x8 pa[2][2];
#pragma unroll
            for (int m = 0; m < 2; ++m)
#pragma unroll
                for (int ks = 0; ks < 2; ++ks) {
                    bf16x8 tt2;
                    tt2[0] = tobf(p[m][2 * ks][0]);
                    tt2[1] = tobf(p[m][2 * ks][1]);
                    tt2[2] = tobf(p[m][2 * ks][2]);
                    tt2[3] = tobf(p[m][2 * ks][3]);
                    tt2[4] = tobf(p[m][2 * ks + 1][0]);
                    tt2[5] = tobf(p[m][2 * ks + 1][1]);
                    tt2[6] = tobf(p[m][2 * ks + 1][2]);
                    tt2[7] = tobf(p[m][2 * ks + 1][3]);
                    pa[m][ks] = tt2;
                }
            __builtin_amdgcn_s_setprio(1);
#pragma unroll
            for (int ks = 0; ks < 2; ++ks) {
#pragma unroll
                for (int dg = 0; dg < 4; ++dg)
#pragma unroll
                    for (int m = 0; m < 2; ++m)
                        acc[m][dg] = __builtin_amdgcn_mfma_f32_16x16x32_bf16(
                            pa[m][ks], vb[ks][dg], acc[m][dg], 0, 0, 0);
#pragma unroll
                for (int m = 0; m < 2; ++m)
                    lsum[m] = __builtin_amdgcn_mfma_f32_16x16x32_bf16(pa[m][ks], vones,
                                                                      lsum[m], 0, 0, 0);
            }
            __builtin_amdgcn_s_setprio(0);
        }
        asm volatile("s_waitcnt vmcnt(0)" ::: "memory");
        __syncthreads();
        cur ^= 1;
    }

#pragma unroll
    for (int m = 0; m < 2; ++m)
#pragma unroll
        for (int j = 0; j < 4; ++j) {
            float inv = 1.f / lsum[m][j];
            int t = qbase + m * 16 + lg * 4 + j;
#pragma unroll
            for (int dg = 0; dg < 4; ++dg) {
                float o = acc[m][dg][j] * inv;
                y[((size_t)(b * TT + t)) * 1024 + h * 64 + dg * 16 + l15] = __float2bfloat16(o);
            }
        }
}

// ---------------------------------------------------------------------------
extern "C" void kernel_launch(void* const* d_in, const int* in_sizes, int n_in,
                              void* d_out, int out_size, void* d_ws, size_t ws_size,
                              hipStream_t stream) {
    const float* x = (const float*)d_in[0];   // [4,2048,1024]
    const float* Wa = (const float*)d_in[1];  // [1024,3072]
    const float* Wp = (const float*)d_in[2];  // [1024,1024]
    float* out = (float*)d_out;               // [4,2048,1024] fp32

    __hip_bfloat16* ws = (__hip_bfloat16*)d_ws;
    __hip_bfloat16* x_bf = ws;                          // 8192*1024
    __hip_bfloat16* WaT = x_bf + (size_t)8192 * 1024;   // 3072*1024 (W_attn^T)
    __hip_bfloat16* WpT = WaT + (size_t)3072 * 1024;    // 1024*1024 (W_proj^T)
    __hip_bfloat16* qkv = WpT + (size_t)1024 * 1024;    // 8192*3072 (V third unused)
    __hip_bfloat16* ybf = qkv + (size_t)8192 * 3072;    // 8192*1024
    __hip_bfloat16* Vt = ybf + (size_t)8192 * 1024;     // 64*64*2048 = 8192*1024

    // fused prep: x cvt + W_attn^T (Q cols scaled by log2e/sqrt(C)) + W_proj^T
    prep_k<<<8192 + 3072 + 1024, 256, 0, stream>>>(x, x_bf, Wa, WaT, Wp, WpT);
    // qkv = x @ W_attn; V columns transposed+key-permuted into Vt via LDS
    gemm4w<true, true><<<dim3(24, 64), 256, 0, stream>>>(x_bf, WaT, qkv, nullptr, Vt,
                                                         8192, 3072, 1024);
    // flash attention -> ybf (1024 four-wave blocks, one super-tile each)
    attn_k<<<dim3(64, 16), 256, 0, stream>>>(qkv, Vt, ybf);
    // out = y @ W_proj   (M=8192, N=1024, K=1024), fp32 out
    gemm4w<false, false><<<dim3(8, 64), 256, 0, stream>>>(ybf, WpT, nullptr, out, nullptr,
                                                          8192, 1024, 1024);
}